// Round 1
// baseline (443.790 us; speedup 1.0000x reference)
//
#include <hip/hip_runtime.h>
#include <stdint.h>

typedef __attribute__((ext_vector_type(8))) short short8;
typedef __attribute__((ext_vector_type(4))) short short4v;
typedef __attribute__((ext_vector_type(4))) float floatx4;
typedef _Float16 half2v __attribute__((ext_vector_type(2)));

__device__ __forceinline__ float b2f(unsigned short u) {
  union { unsigned int i; float f; } v; v.i = ((unsigned int)u) << 16; return v.f;
}
__device__ __forceinline__ unsigned short f2b(float f) {
  union { float f; unsigned int i; } v; v.f = f;
  unsigned int i = v.i;
  return (unsigned short)((i + 0x7FFFu + ((i >> 16) & 1u)) >> 16);
}
__device__ __forceinline__ short4v pack4(float a, float b, float c, float d) {
  short4v r;
  r[0] = (short)f2b(a); r[1] = (short)f2b(b); r[2] = (short)f2b(c); r[3] = (short)f2b(d);
  return r;
}

// global -> LDS 16B per lane. lds_base wave-uniform; HW adds lane*16B.
__device__ __forceinline__ void stage16(const unsigned short* g, unsigned short* lds_base) {
  __builtin_amdgcn_global_load_lds((__attribute__((address_space(1))) const unsigned int*)g,
                                   (__attribute__((address_space(3))) unsigned int*)lds_base,
                                   16, 0, 0);
}

// ---------------------------------------------------------------------------
// BK=32 gemm core, paired-row LDS swizzle (0 bank conflicts),
// swapped-operand MFMA (C rows on lanes -> 8-B packed stores).
// NEW: double-buffered LDS prefetch pipeline (T3-minimum): stage tile t+1
// BEFORE computing tile t, ONE barrier per K-step. The vmcnt(0) drain at the
// barrier now waits for loads issued a full compute-phase earlier, so load
// latency is hidden instead of exposed. Requires K/32 even (768, 1024: ok).
// SWZ=1: 1-D grid 2304 = 8 XCD * 16 ytiles * 18 xtiles.
// ---------------------------------------------------------------------------
template<int SWZ>
__global__ __launch_bounds__(256, 4) void gemm_bt(
    const unsigned short* __restrict__ A, const unsigned short* __restrict__ B,
    unsigned short* __restrict__ Cb, float* __restrict__ Cf,
    const float* __restrict__ rowdiv, const float* __restrict__ bias,
    int K, int lda, int ldb, int ldc,
    long long sA, long long sB, long long sC, long long sRD)
{
  const int tid  = threadIdx.x;
  const int lane = tid & 63;
  const int wave = tid >> 6;
  const int wr = wave >> 1, wc = wave & 1;
  int m0, n0;
  if (SWZ) {
    const int lin  = blockIdx.x;
    const int xcd  = lin & 7;
    const int rem  = lin >> 3;        // 0..287
    const int yloc = rem / 18;
    const int x    = rem - yloc * 18;
    m0 = (xcd * 16 + yloc) * 128;
    n0 = x * 128;
  } else {
    m0 = blockIdx.y * 128;
    n0 = blockIdx.x * 128;
  }
  const int bz = blockIdx.z;
  A += (long long)bz * sA;
  B += (long long)bz * sB;
  const float* rd = rowdiv ? rowdiv + (long long)bz * sRD : (const float*)0;

  // two 8 KB buffers per matrix (buf offset = 4096 shorts)
  __shared__ unsigned short As[2 * 128 * 32];
  __shared__ unsigned short Bs[2 * 128 * 32];

  floatx4 acc[4][4];
#pragma unroll
  for (int i = 0; i < 4; ++i)
#pragma unroll
    for (int j = 0; j < 4; ++j) acc[i][j] = floatx4{0.f, 0.f, 0.f, 0.f};

  // staging source map: lane l -> physical (P=l>>3, p=l&7); t=p^(l>>3);
  // source row_local = 2*(l>>3)+(t>>2), chunk = t&3.
  const int t    = (lane & 7) ^ (lane >> 3);
  const int srow = 2 * (lane >> 3) + (t >> 2);
  const int scol = (t & 3) * 8;
  const unsigned short* ga0 = A + (long long)(m0 + wave * 32 + srow) * lda + scol;
  const unsigned short* ga1 = ga0 + 16LL * lda;
  const unsigned short* gb0 = B + (long long)(n0 + wave * 32 + srow) * ldb + scol;
  const unsigned short* gb1 = gb0 + 16LL * ldb;
  unsigned short* lA0 = As + wave * 1024;
  unsigned short* lA1 = lA0 + 512;
  unsigned short* lB0 = Bs + wave * 1024;
  unsigned short* lB1 = lB0 + 512;

  const int l15  = lane & 15;
  const int q    = lane >> 4;
  const int rofs = (l15 >> 1) * 64 + (((q + 4 * (l15 & 1)) ^ (l15 >> 1)) * 8);

  auto STAGE = [&](int kt, int buf) {
    const int o = buf * 4096;
    stage16(ga0 + kt, lA0 + o);
    stage16(ga1 + kt, lA1 + o);
    stage16(gb0 + kt, lB0 + o);
    stage16(gb1 + kt, lB1 + o);
  };
  auto COMPUTE = [&](int buf) {
    const int o = buf * 4096;
    short8 af[4], bfv[4];
#pragma unroll
    for (int i = 0; i < 4; ++i) af[i]  = *(const short8*)&As[o + (wr * 32 + i * 8) * 64 + rofs];
#pragma unroll
    for (int j = 0; j < 4; ++j) bfv[j] = *(const short8*)&Bs[o + (wc * 32 + j * 8) * 64 + rofs];
#pragma unroll
    for (int i = 0; i < 4; ++i)
#pragma unroll
      for (int j = 0; j < 4; ++j)
        acc[i][j] = __builtin_amdgcn_mfma_f32_16x16x32_bf16(bfv[j], af[i], acc[i][j], 0, 0, 0);
  };

  STAGE(0, 0);
  __syncthreads();
  int kt = 32;
  for (; kt + 32 < K; kt += 64) {
    STAGE(kt, 1);
    COMPUTE(0);
    __syncthreads();
    STAGE(kt + 32, 0);
    COMPUTE(1);
    __syncthreads();
  }
  // kt == K-32 here (K/32 even): last tile
  STAGE(kt, 1);
  COMPUTE(0);
  __syncthreads();
  COMPUTE(1);

  // Epilogue: lane holds C[row=m0+wr*64+i*16+l15][cols n0+wc*64+j*16+q*4 .. +3]
#pragma unroll
  for (int i = 0; i < 4; ++i) {
    const int row = m0 + wr * 64 + i * 16 + l15;
    const float rcp = rd ? __builtin_amdgcn_rcpf(rd[row]) : 1.0f;
#pragma unroll
    for (int j = 0; j < 4; ++j) {
      const int colb = n0 + wc * 64 + j * 16 + q * 4;
      floatx4 v = acc[i][j];
      if (rd) { v[0] *= rcp; v[1] *= rcp; v[2] *= rcp; v[3] *= rcp; }
      if (bias) {
        const float4 bi = *(const float4*)&bias[colb];
        v[0] += bi.x; v[1] += bi.y; v[2] += bi.z; v[3] += bi.w;
      }
      if (Cb) *(short4v*)&Cb[(long long)bz * sC + (long long)row * ldc + colb] = pack4(v[0], v[1], v[2], v[3]);
      else    *(floatx4*)&Cf[(long long)bz * sC + (long long)row * ldc + colb] = v;
    }
  }
}

// ---------------------------------------------------------------------------
// Fused scores + group + exp; QK^T loop now uses the same double-buffered
// prefetch pipeline (768/32 = 24 tiles, even).
// W[b][m][n] = exp(q.k*scale) * (a + (1-a)*gw_m.gw_n);  L[row] += sum exp.
// ---------------------------------------------------------------------------
__global__ __launch_bounds__(256) void score_weights(
    const unsigned short* __restrict__ qkv, const unsigned short* __restrict__ gw,
    unsigned short* __restrict__ Wout, float* __restrict__ L,
    const float* __restrict__ alpha)
{
  const int tid  = threadIdx.x;
  const int lane = tid & 63;
  const int wave = tid >> 6;
  const int wr = wave >> 1, wc = wave & 1;
  const int n0 = blockIdx.x * 128;
  const int m0 = blockIdx.y * 128;
  const int b  = blockIdx.z;

  const int l15 = lane & 15;
  const int q   = lane >> 4;
  const int q8  = q * 8;

  // ---- group phase: direct-from-global frags, K=64 (cols 49..63 zero) ----
  const unsigned short* gq = gw + ((long long)(b * 1024 + m0 + wr * 64)) * 64;
  const unsigned short* gk = gw + ((long long)(b * 1024 + n0 + wc * 64)) * 64;
  floatx4 gacc[4][4];
#pragma unroll
  for (int i = 0; i < 4; ++i)
#pragma unroll
    for (int j = 0; j < 4; ++j) gacc[i][j] = floatx4{0.f, 0.f, 0.f, 0.f};
#pragma unroll
  for (int ks = 0; ks < 2; ++ks) {
    short8 af[4], bfv[4];
#pragma unroll
    for (int i = 0; i < 4; ++i) af[i]  = *(const short8*)&gq[(long long)(i * 16 + l15) * 64 + ks * 32 + q8];
#pragma unroll
    for (int j = 0; j < 4; ++j) bfv[j] = *(const short8*)&gk[(long long)(j * 16 + l15) * 64 + ks * 32 + q8];
#pragma unroll
    for (int i = 0; i < 4; ++i)
#pragma unroll
      for (int j = 0; j < 4; ++j)
        gacc[i][j] = __builtin_amdgcn_mfma_f32_16x16x32_bf16(bfv[j], af[i], gacc[i][j], 0, 0, 0);
  }
  const float aa    = 1.0f / (1.0f + __expf(-alpha[0]));
  const float onema = 1.0f - aa;
  half2v gfp[4][4][2];
#pragma unroll
  for (int i = 0; i < 4; ++i)
#pragma unroll
    for (int j = 0; j < 4; ++j) {
      gfp[i][j][0] = half2v{(_Float16)(aa + onema * gacc[i][j][0]),
                            (_Float16)(aa + onema * gacc[i][j][1])};
      gfp[i][j][1] = half2v{(_Float16)(aa + onema * gacc[i][j][2]),
                            (_Float16)(aa + onema * gacc[i][j][3])};
    }

  // ---- QK^T loop, BK=32 paired-row swizzle, double-buffered prefetch ----
  const unsigned short* Aq = qkv + ((long long)(b * 1024 + m0)) * 2304;        // q cols 0..767
  const unsigned short* Bk = qkv + ((long long)(b * 1024 + n0)) * 2304 + 768;  // k cols 768..1535

  __shared__ unsigned short As[2 * 128 * 32];
  __shared__ unsigned short Bs[2 * 128 * 32];

  floatx4 sacc[4][4];
#pragma unroll
  for (int i = 0; i < 4; ++i)
#pragma unroll
    for (int j = 0; j < 4; ++j) sacc[i][j] = floatx4{0.f, 0.f, 0.f, 0.f};

  const int t    = (lane & 7) ^ (lane >> 3);
  const int srow = 2 * (lane >> 3) + (t >> 2);
  const int scol = (t & 3) * 8;
  const unsigned short* ga0 = Aq + (long long)(wave * 32 + srow) * 2304 + scol;
  const unsigned short* ga1 = ga0 + 16LL * 2304;
  const unsigned short* gb0 = Bk + (long long)(wave * 32 + srow) * 2304 + scol;
  const unsigned short* gb1 = gb0 + 16LL * 2304;
  unsigned short* lA0 = As + wave * 1024;
  unsigned short* lA1 = lA0 + 512;
  unsigned short* lB0 = Bs + wave * 1024;
  unsigned short* lB1 = lB0 + 512;

  const int rofs = (l15 >> 1) * 64 + (((q + 4 * (l15 & 1)) ^ (l15 >> 1)) * 8);

  auto STAGE = [&](int kt, int buf) {
    const int o = buf * 4096;
    stage16(ga0 + kt, lA0 + o);
    stage16(ga1 + kt, lA1 + o);
    stage16(gb0 + kt, lB0 + o);
    stage16(gb1 + kt, lB1 + o);
  };
  auto COMPUTE = [&](int buf) {
    const int o = buf * 4096;
    short8 af[4], bfv[4];
#pragma unroll
    for (int i = 0; i < 4; ++i) af[i]  = *(const short8*)&As[o + (wr * 32 + i * 8) * 64 + rofs];
#pragma unroll
    for (int j = 0; j < 4; ++j) bfv[j] = *(const short8*)&Bs[o + (wc * 32 + j * 8) * 64 + rofs];
#pragma unroll
    for (int i = 0; i < 4; ++i)
#pragma unroll
      for (int j = 0; j < 4; ++j)
        sacc[i][j] = __builtin_amdgcn_mfma_f32_16x16x32_bf16(bfv[j], af[i], sacc[i][j], 0, 0, 0);
  };

  STAGE(0, 0);
  __syncthreads();
  int kt = 32;
  for (; kt + 32 < 768; kt += 64) {
    STAGE(kt, 1);
    COMPUTE(0);
    __syncthreads();
    STAGE(kt + 32, 0);
    COMPUTE(1);
    __syncthreads();
  }
  STAGE(kt, 1);   // kt == 736
  COMPUTE(0);
  __syncthreads();
  COMPUTE(1);

  const float scale = 0.03608439182435161f;  // 768^-0.5
  unsigned short* Wb = Wout + ((long long)b << 20);

#pragma unroll
  for (int i = 0; i < 4; ++i) {
    const int row = m0 + wr * 64 + i * 16 + l15;
    float ls = 0.0f;
#pragma unroll
    for (int j = 0; j < 4; ++j) {
      const int colb = n0 + wc * 64 + j * 16 + q * 4;
      float e0 = __expf(sacc[i][j][0] * scale);
      float e1 = __expf(sacc[i][j][1] * scale);
      float e2 = __expf(sacc[i][j][2] * scale);
      float e3 = __expf(sacc[i][j][3] * scale);
      ls += (e0 + e1) + (e2 + e3);
      *(short4v*)&Wb[(long long)row * 1024 + colb] =
        pack4(e0 * (float)gfp[i][j][0][0], e1 * (float)gfp[i][j][0][1],
              e2 * (float)gfp[i][j][1][0], e3 * (float)gfp[i][j][1][1]);
    }
    ls += __shfl_xor(ls, 16, 64);
    ls += __shfl_xor(ls, 32, 64);
    if (lane < 16) atomicAdd(&L[b * 1024 + row], ls);
  }
}

// gw[row][0..63] = softmax(q_row @ W_gp) padded with zeros (cols 49..63).
__global__ __launch_bounds__(256) void gw_kernel(
    const unsigned short* __restrict__ qkv, const unsigned short* __restrict__ WgpT,
    unsigned short* __restrict__ gw)
{
  const int wave = threadIdx.x >> 6;
  const int lane = threadIdx.x & 63;
  const long long row = (long long)blockIdx.x * 4 + wave;
  const unsigned short* q = qkv + row * 2304;
  float qv[12];
#pragma unroll
  for (int j = 0; j < 12; ++j) qv[j] = b2f(q[lane + 64 * j]);

  float logit = -1e30f;
  for (int g = 0; g < 49; ++g) {
    const unsigned short* wg = WgpT + g * 768;
    float acc = 0.0f;
#pragma unroll
    for (int j = 0; j < 12; ++j) acc += qv[j] * b2f(wg[lane + 64 * j]);
#pragma unroll
    for (int m = 1; m < 64; m <<= 1) acc += __shfl_xor(acc, m, 64);
    if (lane == g) logit = acc;
  }
  float mx = logit;
#pragma unroll
  for (int m = 1; m < 64; m <<= 1) mx = fmaxf(mx, __shfl_xor(mx, m, 64));
  const float e = (lane < 49) ? __expf(logit - mx) : 0.0f;
  float s = e;
#pragma unroll
  for (int m = 1; m < 64; m <<= 1) s += __shfl_xor(s, m, 64);
  gw[row * 64 + lane] = f2b(e / s);
}

__global__ void convert_f2b(const float* __restrict__ in, unsigned short* __restrict__ out, long long n)
{
  long long i = ((long long)blockIdx.x * 256 + threadIdx.x) * 4;
  if (i + 3 >= n) {
    for (long long k = i; k < n; ++k) out[k] = f2b(in[k]);
    return;
  }
  float4 v = *(const float4*)(in + i);
  out[i + 0] = f2b(v.x);
  out[i + 1] = f2b(v.y);
  out[i + 2] = f2b(v.z);
  out[i + 3] = f2b(v.w);
}

__global__ void transpose_f2b(const float* __restrict__ in, unsigned short* __restrict__ out,
                              int R, int C, int ldin, int ldout)
{
  __shared__ unsigned short t[32][33];
  const int c0 = blockIdx.x * 32, r0 = blockIdx.y * 32;
  for (int i = threadIdx.y; i < 32; i += 8) {
    const int r = r0 + i, c = c0 + threadIdx.x;
    if (r < R && c < C) t[i][threadIdx.x] = f2b(in[(long long)r * ldin + c]);
  }
  __syncthreads();
  for (int i = threadIdx.y; i < 32; i += 8) {
    const int r = c0 + i, c = r0 + threadIdx.x;
    if (r < C && c < R) out[(long long)r * ldout + c] = t[threadIdx.x][i];
  }
}

extern "C" void kernel_launch(void* const* d_in, const int* in_sizes, int n_in,
                              void* d_out, int out_size, void* d_ws, size_t ws_size,
                              hipStream_t stream)
{
  const float* x      = (const float*)d_in[0];
  const float* W_qkv  = (const float*)d_in[1];
  const float* b_qkv  = (const float*)d_in[2];
  const float* W_proj = (const float*)d_in[3];
  const float* b_proj = (const float*)d_in[4];
  const float* W_gp   = (const float*)d_in[5];
  const float* alpha  = (const float*)d_in[6];

  char* p = (char*)d_ws;
  auto alloc = [&](size_t bytes) { char* r = p; p += (bytes + 255) & ~255ULL; return r; };
  unsigned short* qkv    = (unsigned short*)alloc(16384ULL * 2304 * 2);   // q|k|v interleaved rows
  unsigned short* xb     = (unsigned short*)alloc(16384ULL * 768 * 2);
  unsigned short* WqkvT  = (unsigned short*)alloc(2304ULL * 768 * 2);
  unsigned short* WprojT = (unsigned short*)alloc(768ULL * 768 * 2);
  unsigned short* WgpT   = (unsigned short*)alloc(49ULL * 768 * 2);
  unsigned short* gwbuf  = (unsigned short*)alloc(16384ULL * 64 * 2);
  float*          Lbuf   = (float*)alloc(16384ULL * 4);
  unsigned short* wmat   = (unsigned short*)alloc(16ULL * 1024 * 1024 * 2);
  unsigned short* vpT    = (unsigned short*)alloc(16ULL * 768 * 1024 * 2); // (v @ W_proj)^T per batch

  const dim3 blk256(256);
  const dim3 tb(32, 8);

  // input conversions / transposes (fp32 -> bf16)
  convert_f2b<<<dim3(12288), blk256, 0, stream>>>(x, xb, 16384LL * 768);
  transpose_f2b<<<dim3(72, 24), tb, 0, stream>>>(W_qkv, WqkvT, 768, 2304, 2304, 768);
  transpose_f2b<<<dim3(24, 24), tb, 0, stream>>>(W_proj, WprojT, 768, 768, 768, 768);
  transpose_f2b<<<dim3(2, 24), tb, 0, stream>>>(W_gp, WgpT, 768, 49, 49, 768);

  // qkv = x @ W_qkv + b_qkv  (XCD-swizzled 1-D grid: 8 xcd * 16 ytiles * 18 xtiles)
  gemm_bt<1><<<dim3(2304, 1, 1), blk256, 0, stream>>>(xb, WqkvT, qkv, (float*)0,
                                                      (const float*)0, b_qkv,
                                                      768, 768, 768, 2304, 0, 0, 0, 0);

  // gw = softmax(q @ W_gp), padded to 64
  gw_kernel<<<dim3(4096), blk256, 0, stream>>>(qkv, WgpT, gwbuf);

  hipMemsetAsync(Lbuf, 0, 16384 * 4, stream);

  // weights (unnormalized) + L
  score_weights<<<dim3(8, 8, 16), blk256, 0, stream>>>(qkv, gwbuf, wmat, Lbuf, alpha);

  // vpT[b][768][1024] = (v @ W_proj)^T = W_proj^T . v^T
  //   gemm_bt: C[n][m] = sum_k WprojT[n][k] * v[m][k]; A=WprojT (shared), B=v rows of qkv
  gemm_bt<0><<<dim3(8, 6, 16), blk256, 0, stream>>>(WprojT, qkv + 1536, vpT, (float*)0,
                                                    (const float*)0, (const float*)0,
                                                    768, 768, 2304, 1024,
                                                    0, 1024LL * 2304, 768LL * 1024, 0);

  // out[m][n] = (1/L[m]) * sum_k wmat[m][k] * vpT[n][k] + b_proj[n]   (fp32 out)
  gemm_bt<0><<<dim3(6, 8, 16), blk256, 0, stream>>>(wmat, vpT, (unsigned short*)0, (float*)d_out,
                                                    Lbuf, b_proj,
                                                    1024, 1024, 1024, 768,
                                                    1024LL * 1024, 768LL * 1024, 1024LL * 768, 1024);
}

// Round 2
// 437.561 us; speedup vs baseline: 1.0142x; 1.0142x over previous
//
#include <hip/hip_runtime.h>
#include <stdint.h>

typedef __attribute__((ext_vector_type(8))) short short8;
typedef __attribute__((ext_vector_type(4))) short short4v;
typedef __attribute__((ext_vector_type(4))) float floatx4;
typedef _Float16 half2v __attribute__((ext_vector_type(2)));

__device__ __forceinline__ float b2f(unsigned short u) {
  union { unsigned int i; float f; } v; v.i = ((unsigned int)u) << 16; return v.f;
}
__device__ __forceinline__ unsigned short f2b(float f) {
  union { float f; unsigned int i; } v; v.f = f;
  unsigned int i = v.i;
  return (unsigned short)((i + 0x7FFFu + ((i >> 16) & 1u)) >> 16);
}
__device__ __forceinline__ short4v pack4(float a, float b, float c, float d) {
  short4v r;
  r[0] = (short)f2b(a); r[1] = (short)f2b(b); r[2] = (short)f2b(c); r[3] = (short)f2b(d);
  return r;
}

// global -> LDS 16B per lane. lds_base wave-uniform; HW adds lane*16B.
__device__ __forceinline__ void stage16(const unsigned short* g, unsigned short* lds_base) {
  __builtin_amdgcn_global_load_lds((__attribute__((address_space(1))) const unsigned int*)g,
                                   (__attribute__((address_space(3))) unsigned int*)lds_base,
                                   16, 0, 0);
}

// ---------------------------------------------------------------------------
// 256x256 deep-pipelined GEMM engine (T3+T4+T5 per regime-gate: 256²+phases).
// BK=32, 512 threads = 8 waves (2 row-halves x 4 col-quarters), per-wave
// output 128x64 (acc[8][4]). LDS: 3-buffer ring, 32 KB each (A 16K | B 16K),
// paired-row zero-conflict swizzle carried over from the verified 128² core.
// Pipeline: prefetch distance 2 K-tiles; per K-tile 2 phases x 16 MFMA with
// raw s_barrier + lgkmcnt(0) + sched_barrier(0) (rule #18) + setprio around
// MFMA; ONE counted s_waitcnt vmcnt(4) per K-tile (never 0 in steady state):
// tile t+1's loads (issued during t-1) get ~3-4 phases of MFMA cover.
// Buffer safety: stage for t+2 targets buf[(t-1)%3], whose last reads
// completed before the end-of-(t-1) barrier that precedes the stage issue.
// ---------------------------------------------------------------------------
template<int SWZ>
__global__ __launch_bounds__(512, 2) void gemm256(
    const unsigned short* __restrict__ A, const unsigned short* __restrict__ B,
    unsigned short* __restrict__ Cb, float* __restrict__ Cf,
    const float* __restrict__ rowdiv, const float* __restrict__ bias,
    int K, int lda, int ldb, int ldc,
    long long sA, long long sB, long long sC, long long sRD)
{
  const int tid  = threadIdx.x;
  const int lane = tid & 63;
  const int wave = tid >> 6;          // 0..7
  const int wr = wave >> 2;           // 0..1  (row half: 128 rows)
  const int wc = wave & 3;            // 0..3  (col quarter: 64 cols)
  int m0, n0;
  if (SWZ) {
    // 576 = 8 xcd * 8 yloc * 9 x ; bijective (576 % 8 == 0)
    const int lin  = blockIdx.x;
    const int xcd  = lin & 7;
    const int rem  = lin >> 3;        // 0..71
    const int yloc = rem / 9;
    const int x    = rem - yloc * 9;
    m0 = (xcd * 8 + yloc) * 256;
    n0 = x * 256;
  } else {
    m0 = blockIdx.y * 256;
    n0 = blockIdx.x * 256;
  }
  const int bz = blockIdx.z;
  A += (long long)bz * sA;
  B += (long long)bz * sB;
  const float* rd = rowdiv ? rowdiv + (long long)bz * sRD : (const float*)0;

  // 3 ring buffers x (A: 8192 shorts | B: 8192 shorts) = 96 KB
  __shared__ __align__(16) unsigned short lds[3 * 16384];

  floatx4 acc[8][4];
#pragma unroll
  for (int i = 0; i < 8; ++i)
#pragma unroll
    for (int j = 0; j < 4; ++j) acc[i][j] = floatx4{0.f, 0.f, 0.f, 0.f};

  // staging source map (verified zero-conflict pairing): lane l ->
  // t=p^(l>>3); source row_local = 2*(l>>3)+(t>>2), chunk col = (t&3)*8.
  const int t    = (lane & 7) ^ (lane >> 3);
  const int srow = 2 * (lane >> 3) + (t >> 2);
  const int scol = (t & 3) * 8;
  const unsigned short* ga0 = A + (long long)(m0 + wave * 32 + srow) * lda + scol;
  const unsigned short* ga1 = ga0 + 16LL * lda;
  const unsigned short* gb0 = B + (long long)(n0 + wave * 32 + srow) * ldb + scol;
  const unsigned short* gb1 = gb0 + 16LL * ldb;

  const int l15  = lane & 15;
  const int q    = lane >> 4;
  const int rofs = (l15 >> 1) * 64 + (((q + 4 * (l15 & 1)) ^ (l15 >> 1)) * 8);

  short8 af[4], bfv[4];

  auto STAGE_A = [&](int kt, int buf) {
    unsigned short* d = lds + buf * 16384 + wave * 1024;
    stage16(ga0 + kt, d);
    stage16(ga1 + kt, d + 512);
  };
  auto STAGE_B = [&](int kt, int buf) {
    unsigned short* d = lds + buf * 16384 + 8192 + wave * 1024;
    stage16(gb0 + kt, d);
    stage16(gb1 + kt, d + 512);
  };
  auto READ_A = [&](int buf, int base) {   // frags i = base..base+3
    const unsigned short* Ab = lds + buf * 16384;
#pragma unroll
    for (int i = 0; i < 4; ++i)
      af[i] = *(const short8*)&Ab[(wr * 64 + (base + i) * 8) * 64 + rofs];
  };
  auto READ_B = [&](int buf) {
    const unsigned short* Bb = lds + buf * 16384 + 8192;
#pragma unroll
    for (int j = 0; j < 4; ++j)
      bfv[j] = *(const short8*)&Bb[(wc * 32 + j * 8) * 64 + rofs];
  };
  auto MFMA_BLK = [&](int h) {             // acc rows h*4 .. h*4+3
#pragma unroll
    for (int i = 0; i < 4; ++i)
#pragma unroll
      for (int j = 0; j < 4; ++j)
        acc[h * 4 + i][j] = __builtin_amdgcn_mfma_f32_16x16x32_bf16(bfv[j], af[i], acc[h * 4 + i][j], 0, 0, 0);
  };

  const int nt = K >> 5;                   // 24 or 32 here (>= 3 required)
  int cur = 0;

  // ---- prologue: stage tiles 0 and 1, wait tile 0 (4 newest outstanding) ----
  STAGE_A(0, 0);  STAGE_B(0, 0);
  STAGE_A(32, 1); STAGE_B(32, 1);
  asm volatile("s_waitcnt vmcnt(4)" ::: "memory");
  __builtin_amdgcn_sched_barrier(0);
  __builtin_amdgcn_s_barrier();

  // ---- steady state ----
  for (int tt = 0; tt < nt - 2; ++tt) {
    const int nb  = (cur == 0) ? 2 : cur - 1;   // (cur+2)%3
    const int kt2 = (tt + 2) << 5;
    // phase 0: read lo-frags + B, stage A(t+2), barrier, 16 MFMA
    READ_B(cur);
    READ_A(cur, 0);
    STAGE_A(kt2, nb);
    __builtin_amdgcn_sched_barrier(0);
    __builtin_amdgcn_s_barrier();
    asm volatile("s_waitcnt lgkmcnt(0)" ::: "memory");
    __builtin_amdgcn_sched_barrier(0);
    __builtin_amdgcn_s_setprio(1);
    MFMA_BLK(0);
    __builtin_amdgcn_s_setprio(0);
    __builtin_amdgcn_sched_barrier(0);
    __builtin_amdgcn_s_barrier();
    // phase 1: read hi-frags, stage B(t+2), barrier, 16 MFMA, counted vmcnt
    READ_A(cur, 4);
    STAGE_B(kt2, nb);
    __builtin_amdgcn_sched_barrier(0);
    __builtin_amdgcn_s_barrier();
    asm volatile("s_waitcnt lgkmcnt(0)" ::: "memory");
    __builtin_amdgcn_sched_barrier(0);
    __builtin_amdgcn_s_setprio(1);
    MFMA_BLK(1);
    __builtin_amdgcn_s_setprio(0);
    asm volatile("s_waitcnt vmcnt(4)" ::: "memory");   // t+1 landed; t+2 in flight
    __builtin_amdgcn_sched_barrier(0);
    __builtin_amdgcn_s_barrier();
    cur = (cur == 2) ? 0 : cur + 1;
  }

  // ---- tile nt-2: no staging; drain remaining loads for tile nt-1 ----
  {
    READ_B(cur);
    READ_A(cur, 0);
    __builtin_amdgcn_sched_barrier(0);
    __builtin_amdgcn_s_barrier();
    asm volatile("s_waitcnt lgkmcnt(0)" ::: "memory");
    __builtin_amdgcn_sched_barrier(0);
    __builtin_amdgcn_s_setprio(1);
    MFMA_BLK(0);
    __builtin_amdgcn_s_setprio(0);
    __builtin_amdgcn_sched_barrier(0);
    __builtin_amdgcn_s_barrier();
    READ_A(cur, 4);
    __builtin_amdgcn_sched_barrier(0);
    __builtin_amdgcn_s_barrier();
    asm volatile("s_waitcnt lgkmcnt(0)" ::: "memory");
    __builtin_amdgcn_sched_barrier(0);
    __builtin_amdgcn_s_setprio(1);
    MFMA_BLK(1);
    __builtin_amdgcn_s_setprio(0);
    asm volatile("s_waitcnt vmcnt(0)" ::: "memory");
    __builtin_amdgcn_sched_barrier(0);
    __builtin_amdgcn_s_barrier();
    cur = (cur == 2) ? 0 : cur + 1;
  }
  // ---- tile nt-1 (last): compute only ----
  {
    READ_B(cur);
    READ_A(cur, 0);
    __builtin_amdgcn_sched_barrier(0);
    __builtin_amdgcn_s_barrier();
    asm volatile("s_waitcnt lgkmcnt(0)" ::: "memory");
    __builtin_amdgcn_sched_barrier(0);
    __builtin_amdgcn_s_setprio(1);
    MFMA_BLK(0);
    __builtin_amdgcn_s_setprio(0);
    __builtin_amdgcn_sched_barrier(0);
    __builtin_amdgcn_s_barrier();
    READ_A(cur, 4);
    asm volatile("s_waitcnt lgkmcnt(0)" ::: "memory");
    __builtin_amdgcn_sched_barrier(0);
    __builtin_amdgcn_s_setprio(1);
    MFMA_BLK(1);
    __builtin_amdgcn_s_setprio(0);
  }

  // Epilogue: lane holds C[row=m0+wr*128+i*16+l15][cols n0+wc*64+j*16+q*4 .. +3]
#pragma unroll
  for (int i = 0; i < 8; ++i) {
    const int row = m0 + wr * 128 + i * 16 + l15;
    const float rcp = rd ? __builtin_amdgcn_rcpf(rd[row]) : 1.0f;
#pragma unroll
    for (int j = 0; j < 4; ++j) {
      const int colb = n0 + wc * 64 + j * 16 + q * 4;
      floatx4 v = acc[i][j];
      if (rd) { v[0] *= rcp; v[1] *= rcp; v[2] *= rcp; v[3] *= rcp; }
      if (bias) {
        const float4 bi = *(const float4*)&bias[colb];
        v[0] += bi.x; v[1] += bi.y; v[2] += bi.z; v[3] += bi.w;
      }
      if (Cb) *(short4v*)&Cb[(long long)bz * sC + (long long)row * ldc + colb] = pack4(v[0], v[1], v[2], v[3]);
      else    *(floatx4*)&Cf[(long long)bz * sC + (long long)row * ldc + colb] = v;
    }
  }
}

// ---------------------------------------------------------------------------
// Fused scores + group + exp, paired-row swizzle in the QK^T loop.
// (round-0 form: the 128²/4-wave quadrant is proven-null for deep phasing,
//  so this keeps the simple single-buffer loop.)
// W[b][m][n] = exp(q.k*scale) * (a + (1-a)*gw_m.gw_n);  L[row] += sum exp.
// ---------------------------------------------------------------------------
__global__ __launch_bounds__(256) void score_weights(
    const unsigned short* __restrict__ qkv, const unsigned short* __restrict__ gw,
    unsigned short* __restrict__ Wout, float* __restrict__ L,
    const float* __restrict__ alpha)
{
  const int tid  = threadIdx.x;
  const int lane = tid & 63;
  const int wave = tid >> 6;
  const int wr = wave >> 1, wc = wave & 1;
  const int n0 = blockIdx.x * 128;
  const int m0 = blockIdx.y * 128;
  const int b  = blockIdx.z;

  const int l15 = lane & 15;
  const int q   = lane >> 4;
  const int q8  = q * 8;

  // ---- group phase: direct-from-global frags, K=64 (cols 49..63 zero) ----
  const unsigned short* gq = gw + ((long long)(b * 1024 + m0 + wr * 64)) * 64;
  const unsigned short* gk = gw + ((long long)(b * 1024 + n0 + wc * 64)) * 64;
  floatx4 gacc[4][4];
#pragma unroll
  for (int i = 0; i < 4; ++i)
#pragma unroll
    for (int j = 0; j < 4; ++j) gacc[i][j] = floatx4{0.f, 0.f, 0.f, 0.f};
#pragma unroll
  for (int ks = 0; ks < 2; ++ks) {
    short8 af[4], bfv[4];
#pragma unroll
    for (int i = 0; i < 4; ++i) af[i]  = *(const short8*)&gq[(long long)(i * 16 + l15) * 64 + ks * 32 + q8];
#pragma unroll
    for (int j = 0; j < 4; ++j) bfv[j] = *(const short8*)&gk[(long long)(j * 16 + l15) * 64 + ks * 32 + q8];
#pragma unroll
    for (int i = 0; i < 4; ++i)
#pragma unroll
      for (int j = 0; j < 4; ++j)
        gacc[i][j] = __builtin_amdgcn_mfma_f32_16x16x32_bf16(bfv[j], af[i], gacc[i][j], 0, 0, 0);
  }
  const float aa    = 1.0f / (1.0f + __expf(-alpha[0]));
  const float onema = 1.0f - aa;
  half2v gfp[4][4][2];
#pragma unroll
  for (int i = 0; i < 4; ++i)
#pragma unroll
    for (int j = 0; j < 4; ++j) {
      gfp[i][j][0] = half2v{(_Float16)(aa + onema * gacc[i][j][0]),
                            (_Float16)(aa + onema * gacc[i][j][1])};
      gfp[i][j][1] = half2v{(_Float16)(aa + onema * gacc[i][j][2]),
                            (_Float16)(aa + onema * gacc[i][j][3])};
    }

  // ---- QK^T loop, BK=32 paired-row swizzle ----
  const unsigned short* Aq = qkv + ((long long)(b * 1024 + m0)) * 2304;        // q cols 0..767
  const unsigned short* Bk = qkv + ((long long)(b * 1024 + n0)) * 2304 + 768;  // k cols 768..1535

  __shared__ unsigned short As[128 * 32];
  __shared__ unsigned short Bs[128 * 32];

  floatx4 sacc[4][4];
#pragma unroll
  for (int i = 0; i < 4; ++i)
#pragma unroll
    for (int j = 0; j < 4; ++j) sacc[i][j] = floatx4{0.f, 0.f, 0.f, 0.f};

  const int t    = (lane & 7) ^ (lane >> 3);
  const int srow = 2 * (lane >> 3) + (t >> 2);
  const int scol = (t & 3) * 8;
  const unsigned short* ga0 = Aq + (long long)(wave * 32 + srow) * 2304 + scol;
  const unsigned short* ga1 = ga0 + 16LL * 2304;
  const unsigned short* gb0 = Bk + (long long)(wave * 32 + srow) * 2304 + scol;
  const unsigned short* gb1 = gb0 + 16LL * 2304;
  unsigned short* lA0 = As + wave * 1024;
  unsigned short* lA1 = lA0 + 512;
  unsigned short* lB0 = Bs + wave * 1024;
  unsigned short* lB1 = lB0 + 512;

  const int rofs = (l15 >> 1) * 64 + (((q + 4 * (l15 & 1)) ^ (l15 >> 1)) * 8);

  for (int kt = 0; kt < 768; kt += 32) {
    __syncthreads();
    stage16(ga0 + kt, lA0);
    stage16(ga1 + kt, lA1);
    stage16(gb0 + kt, lB0);
    stage16(gb1 + kt, lB1);
    __syncthreads();
    short8 af[4], bfv[4];
#pragma unroll
    for (int i = 0; i < 4; ++i) af[i]  = *(const short8*)&As[(wr * 32 + i * 8) * 64 + rofs];
#pragma unroll
    for (int j = 0; j < 4; ++j) bfv[j] = *(const short8*)&Bs[(wc * 32 + j * 8) * 64 + rofs];
#pragma unroll
    for (int i = 0; i < 4; ++i)
#pragma unroll
      for (int j = 0; j < 4; ++j)
        sacc[i][j] = __builtin_amdgcn_mfma_f32_16x16x32_bf16(bfv[j], af[i], sacc[i][j], 0, 0, 0);
  }

  const float scale = 0.03608439182435161f;  // 768^-0.5
  unsigned short* Wb = Wout + ((long long)b << 20);

#pragma unroll
  for (int i = 0; i < 4; ++i) {
    const int row = m0 + wr * 64 + i * 16 + l15;
    float ls = 0.0f;
#pragma unroll
    for (int j = 0; j < 4; ++j) {
      const int colb = n0 + wc * 64 + j * 16 + q * 4;
      float e0 = __expf(sacc[i][j][0] * scale);
      float e1 = __expf(sacc[i][j][1] * scale);
      float e2 = __expf(sacc[i][j][2] * scale);
      float e3 = __expf(sacc[i][j][3] * scale);
      ls += (e0 + e1) + (e2 + e3);
      *(short4v*)&Wb[(long long)row * 1024 + colb] =
        pack4(e0 * (float)gfp[i][j][0][0], e1 * (float)gfp[i][j][0][1],
              e2 * (float)gfp[i][j][1][0], e3 * (float)gfp[i][j][1][1]);
    }
    ls += __shfl_xor(ls, 16, 64);
    ls += __shfl_xor(ls, 32, 64);
    if (lane < 16) atomicAdd(&L[b * 1024 + row], ls);
  }
}

// gw[row][0..63] = softmax(q_row @ W_gp) padded with zeros (cols 49..63).
__global__ __launch_bounds__(256) void gw_kernel(
    const unsigned short* __restrict__ qkv, const unsigned short* __restrict__ WgpT,
    unsigned short* __restrict__ gw)
{
  const int wave = threadIdx.x >> 6;
  const int lane = threadIdx.x & 63;
  const long long row = (long long)blockIdx.x * 4 + wave;
  const unsigned short* q = qkv + row * 2304;
  float qv[12];
#pragma unroll
  for (int j = 0; j < 12; ++j) qv[j] = b2f(q[lane + 64 * j]);

  float logit = -1e30f;
  for (int g = 0; g < 49; ++g) {
    const unsigned short* wg = WgpT + g * 768;
    float acc = 0.0f;
#pragma unroll
    for (int j = 0; j < 12; ++j) acc += qv[j] * b2f(wg[lane + 64 * j]);
#pragma unroll
    for (int m = 1; m < 64; m <<= 1) acc += __shfl_xor(acc, m, 64);
    if (lane == g) logit = acc;
  }
  float mx = logit;
#pragma unroll
  for (int m = 1; m < 64; m <<= 1) mx = fmaxf(mx, __shfl_xor(mx, m, 64));
  const float e = (lane < 49) ? __expf(logit - mx) : 0.0f;
  float s = e;
#pragma unroll
  for (int m = 1; m < 64; m <<= 1) s += __shfl_xor(s, m, 64);
  gw[row * 64 + lane] = f2b(e / s);
}

__global__ void convert_f2b(const float* __restrict__ in, unsigned short* __restrict__ out, long long n)
{
  long long i = ((long long)blockIdx.x * 256 + threadIdx.x) * 4;
  if (i + 3 >= n) {
    for (long long k = i; k < n; ++k) out[k] = f2b(in[k]);
    return;
  }
  float4 v = *(const float4*)(in + i);
  out[i + 0] = f2b(v.x);
  out[i + 1] = f2b(v.y);
  out[i + 2] = f2b(v.z);
  out[i + 3] = f2b(v.w);
}

__global__ void transpose_f2b(const float* __restrict__ in, unsigned short* __restrict__ out,
                              int R, int C, int ldin, int ldout)
{
  __shared__ unsigned short t[32][33];
  const int c0 = blockIdx.x * 32, r0 = blockIdx.y * 32;
  for (int i = threadIdx.y; i < 32; i += 8) {
    const int r = r0 + i, c = c0 + threadIdx.x;
    if (r < R && c < C) t[i][threadIdx.x] = f2b(in[(long long)r * ldin + c]);
  }
  __syncthreads();
  for (int i = threadIdx.y; i < 32; i += 8) {
    const int r = c0 + i, c = r0 + threadIdx.x;
    if (r < C && c < R) out[(long long)r * ldout + c] = t[threadIdx.x][i];
  }
}

extern "C" void kernel_launch(void* const* d_in, const int* in_sizes, int n_in,
                              void* d_out, int out_size, void* d_ws, size_t ws_size,
                              hipStream_t stream)
{
  const float* x      = (const float*)d_in[0];
  const float* W_qkv  = (const float*)d_in[1];
  const float* b_qkv  = (const float*)d_in[2];
  const float* W_proj = (const float*)d_in[3];
  const float* b_proj = (const float*)d_in[4];
  const float* W_gp   = (const float*)d_in[5];
  const float* alpha  = (const float*)d_in[6];

  char* p = (char*)d_ws;
  auto alloc = [&](size_t bytes) { char* r = p; p += (bytes + 255) & ~255ULL; return r; };
  unsigned short* qkv    = (unsigned short*)alloc(16384ULL * 2304 * 2);   // q|k|v interleaved rows
  unsigned short* xb     = (unsigned short*)alloc(16384ULL * 768 * 2);
  unsigned short* WqkvT  = (unsigned short*)alloc(2304ULL * 768 * 2);
  unsigned short* WprojT = (unsigned short*)alloc(768ULL * 768 * 2);
  unsigned short* WgpT   = (unsigned short*)alloc(49ULL * 768 * 2);
  unsigned short* gwbuf  = (unsigned short*)alloc(16384ULL * 64 * 2);
  float*          Lbuf   = (float*)alloc(16384ULL * 4);
  unsigned short* wmat   = (unsigned short*)alloc(16ULL * 1024 * 1024 * 2);
  unsigned short* vpT    = (unsigned short*)alloc(16ULL * 768 * 1024 * 2); // (v @ W_proj)^T per batch

  const dim3 blk256(256);
  const dim3 blk512(512);
  const dim3 tb(32, 8);

  // input conversions / transposes (fp32 -> bf16)
  convert_f2b<<<dim3(12288), blk256, 0, stream>>>(x, xb, 16384LL * 768);
  transpose_f2b<<<dim3(72, 24), tb, 0, stream>>>(W_qkv, WqkvT, 768, 2304, 2304, 768);
  transpose_f2b<<<dim3(24, 24), tb, 0, stream>>>(W_proj, WprojT, 768, 768, 768, 768);
  transpose_f2b<<<dim3(2, 24), tb, 0, stream>>>(W_gp, WgpT, 768, 49, 49, 768);

  // qkv = x @ W_qkv + b_qkv   (256² engine; 576 = 8 xcd * 8 ytiles * 9 xtiles)
  gemm256<1><<<dim3(576, 1, 1), blk512, 0, stream>>>(xb, WqkvT, qkv, (float*)0,
                                                     (const float*)0, b_qkv,
                                                     768, 768, 768, 2304, 0, 0, 0, 0);

  // gw = softmax(q @ W_gp), padded to 64
  gw_kernel<<<dim3(4096), blk256, 0, stream>>>(qkv, WgpT, gwbuf);

  hipMemsetAsync(Lbuf, 0, 16384 * 4, stream);

  // weights (unnormalized) + L
  score_weights<<<dim3(8, 8, 16), blk256, 0, stream>>>(qkv, gwbuf, wmat, Lbuf, alpha);

  // vpT[b][768][1024] = (v @ W_proj)^T = W_proj^T . v^T
  //   C[n][m] = sum_k WprojT[n][k] * v[m][k]; A=WprojT (shared), B=v rows of qkv
  gemm256<0><<<dim3(4, 3, 16), blk512, 0, stream>>>(WprojT, qkv + 1536, vpT, (float*)0,
                                                    (const float*)0, (const float*)0,
                                                    768, 768, 2304, 1024,
                                                    0, 1024LL * 2304, 768LL * 1024, 0);

  // out[m][n] = (1/L[m]) * sum_k wmat[m][k] * vpT[n][k] + b_proj[n]   (fp32 out)
  gemm256<0><<<dim3(3, 4, 16), blk512, 0, stream>>>(wmat, vpT, (unsigned short*)0, (float*)d_out,
                                                    Lbuf, b_proj,
                                                    1024, 1024, 1024, 768,
                                                    1024LL * 1024, 768LL * 1024, 1024LL * 768, 1024);
}

// Round 3
// 424.512 us; speedup vs baseline: 1.0454x; 1.0307x over previous
//
#include <hip/hip_runtime.h>
#include <stdint.h>

typedef __attribute__((ext_vector_type(8))) short short8;
typedef __attribute__((ext_vector_type(4))) short short4v;
typedef __attribute__((ext_vector_type(4))) float floatx4;
typedef _Float16 half2v __attribute__((ext_vector_type(2)));

__device__ __forceinline__ float b2f(unsigned short u) {
  union { unsigned int i; float f; } v; v.i = ((unsigned int)u) << 16; return v.f;
}
__device__ __forceinline__ unsigned short f2b(float f) {
  union { float f; unsigned int i; } v; v.f = f;
  unsigned int i = v.i;
  return (unsigned short)((i + 0x7FFFu + ((i >> 16) & 1u)) >> 16);
}
__device__ __forceinline__ short4v pack4(float a, float b, float c, float d) {
  short4v r;
  r[0] = (short)f2b(a); r[1] = (short)f2b(b); r[2] = (short)f2b(c); r[3] = (short)f2b(d);
  return r;
}

// global -> LDS 16B per lane. lds_base wave-uniform; HW adds lane*16B.
__device__ __forceinline__ void stage16(const unsigned short* g, unsigned short* lds_base) {
  __builtin_amdgcn_global_load_lds((__attribute__((address_space(1))) const unsigned int*)g,
                                   (__attribute__((address_space(3))) unsigned int*)lds_base,
                                   16, 0, 0);
}

// ---------------------------------------------------------------------------
// 256x256 deep-pipelined GEMM engine. BK=32, 512 threads = 8 waves
// (2 row-halves x 4 col-quarters), per-wave output 128x64 (acc[8][4]).
// LDS: 3-buffer ring x 32 KB (A 16K | B 16K), paired-row zero-conflict
// swizzle. Prefetch distance 2 K-tiles; ONE counted s_waitcnt vmcnt(4) per
// K-tile (never 0 in steady state); vmcnt-then-barrier = inter-wave
// completion guarantee for the staged tile.
// r3 change vs r2: NO sched_barrier(0), NO explicit lgkmcnt asm — the
// compiler tracks its own ds_reads (m97: fine-grained lgkmcnt; m141:
// sched_barrier(0) pinning is a 1.7x regression; m203: plain reads ==
// asm reads on the working 8-phase template).
// ---------------------------------------------------------------------------
template<int SWZ>
__global__ __launch_bounds__(512, 2) void gemm256(
    const unsigned short* __restrict__ A, const unsigned short* __restrict__ B,
    unsigned short* __restrict__ Cb, float* __restrict__ Cf,
    const float* __restrict__ rowdiv, const float* __restrict__ bias,
    int K, int lda, int ldb, int ldc,
    long long sA, long long sB, long long sC, long long sRD)
{
  const int tid  = threadIdx.x;
  const int lane = tid & 63;
  const int wave = tid >> 6;          // 0..7
  const int wr = wave >> 2;           // 0..1  (row half: 128 rows)
  const int wc = wave & 3;            // 0..3  (col quarter: 64 cols)
  int m0, n0;
  if (SWZ) {
    // 576 = 8 xcd * 8 yloc * 9 x ; bijective (576 % 8 == 0)
    const int lin  = blockIdx.x;
    const int xcd  = lin & 7;
    const int rem  = lin >> 3;        // 0..71
    const int yloc = rem / 9;
    const int x    = rem - yloc * 9;
    m0 = (xcd * 8 + yloc) * 256;
    n0 = x * 256;
  } else {
    m0 = blockIdx.y * 256;
    n0 = blockIdx.x * 256;
  }
  const int bz = blockIdx.z;
  A += (long long)bz * sA;
  B += (long long)bz * sB;
  const float* rd = rowdiv ? rowdiv + (long long)bz * sRD : (const float*)0;

  // 3 ring buffers x (A: 8192 shorts | B: 8192 shorts) = 96 KB
  __shared__ __align__(16) unsigned short lds[3 * 16384];

  floatx4 acc[8][4];
#pragma unroll
  for (int i = 0; i < 8; ++i)
#pragma unroll
    for (int j = 0; j < 4; ++j) acc[i][j] = floatx4{0.f, 0.f, 0.f, 0.f};

  // staging source map (verified zero-conflict pairing): lane l ->
  // t=p^(l>>3); source row_local = 2*(l>>3)+(t>>2), chunk col = (t&3)*8.
  const int t    = (lane & 7) ^ (lane >> 3);
  const int srow = 2 * (lane >> 3) + (t >> 2);
  const int scol = (t & 3) * 8;
  const unsigned short* ga0 = A + (long long)(m0 + wave * 32 + srow) * lda + scol;
  const unsigned short* ga1 = ga0 + 16LL * lda;
  const unsigned short* gb0 = B + (long long)(n0 + wave * 32 + srow) * ldb + scol;
  const unsigned short* gb1 = gb0 + 16LL * ldb;

  const int l15  = lane & 15;
  const int q    = lane >> 4;
  const int rofs = (l15 >> 1) * 64 + (((q + 4 * (l15 & 1)) ^ (l15 >> 1)) * 8);

  short8 af[4], bfv[4];

  auto STAGE_A = [&](int kt, int buf) {
    unsigned short* d = lds + buf * 16384 + wave * 1024;
    stage16(ga0 + kt, d);
    stage16(ga1 + kt, d + 512);
  };
  auto STAGE_B = [&](int kt, int buf) {
    unsigned short* d = lds + buf * 16384 + 8192 + wave * 1024;
    stage16(gb0 + kt, d);
    stage16(gb1 + kt, d + 512);
  };
  auto READ_A = [&](int buf, int base) {   // frags i = base..base+3
    const unsigned short* Ab = lds + buf * 16384;
#pragma unroll
    for (int i = 0; i < 4; ++i)
      af[i] = *(const short8*)&Ab[(wr * 64 + (base + i) * 8) * 64 + rofs];
  };
  auto READ_B = [&](int buf) {
    const unsigned short* Bb = lds + buf * 16384 + 8192;
#pragma unroll
    for (int j = 0; j < 4; ++j)
      bfv[j] = *(const short8*)&Bb[(wc * 32 + j * 8) * 64 + rofs];
  };
  auto MFMA_BLK = [&](int h) {             // acc rows h*4 .. h*4+3
#pragma unroll
    for (int i = 0; i < 4; ++i)
#pragma unroll
      for (int j = 0; j < 4; ++j)
        acc[h * 4 + i][j] = __builtin_amdgcn_mfma_f32_16x16x32_bf16(bfv[j], af[i], acc[h * 4 + i][j], 0, 0, 0);
  };

  const int nt = K >> 5;                   // 24 or 32 here (>= 3 required)
  int cur = 0;

  // ---- prologue: stage tiles 0 and 1; own-wave vmcnt then barrier ==
  // all waves' tile-0 loads complete before anyone reads ----
  STAGE_A(0, 0);  STAGE_B(0, 0);
  STAGE_A(32, 1); STAGE_B(32, 1);
  asm volatile("s_waitcnt vmcnt(4)" ::: "memory");
  __builtin_amdgcn_s_barrier();

  // ---- steady state ----
  for (int tt = 0; tt < nt - 2; ++tt) {
    const int nb  = (cur == 0) ? 2 : cur - 1;   // (cur+2)%3
    const int kt2 = (tt + 2) << 5;
    // phase 0: read lo-frags + B, stage A(t+2), barrier, 16 MFMA
    READ_B(cur);
    READ_A(cur, 0);
    STAGE_A(kt2, nb);
    __builtin_amdgcn_s_barrier();
    __builtin_amdgcn_s_setprio(1);
    MFMA_BLK(0);
    __builtin_amdgcn_s_setprio(0);
    __builtin_amdgcn_s_barrier();
    // phase 1: read hi-frags, stage B(t+2), barrier, 16 MFMA, counted vmcnt
    READ_A(cur, 4);
    STAGE_B(kt2, nb);
    __builtin_amdgcn_s_barrier();
    __builtin_amdgcn_s_setprio(1);
    MFMA_BLK(1);
    __builtin_amdgcn_s_setprio(0);
    asm volatile("s_waitcnt vmcnt(4)" ::: "memory");   // t+1 landed; t+2 in flight
    __builtin_amdgcn_s_barrier();
    cur = (cur == 2) ? 0 : cur + 1;
  }

  // ---- tile nt-2: no staging; drain all loads so tile nt-1 is ready ----
  {
    READ_B(cur);
    READ_A(cur, 0);
    __builtin_amdgcn_s_barrier();
    __builtin_amdgcn_s_setprio(1);
    MFMA_BLK(0);
    __builtin_amdgcn_s_setprio(0);
    __builtin_amdgcn_s_barrier();
    READ_A(cur, 4);
    __builtin_amdgcn_s_setprio(1);
    MFMA_BLK(1);
    __builtin_amdgcn_s_setprio(0);
    asm volatile("s_waitcnt vmcnt(0)" ::: "memory");
    __builtin_amdgcn_s_barrier();
    cur = (cur == 2) ? 0 : cur + 1;
  }
  // ---- tile nt-1 (last): compute only ----
  {
    READ_B(cur);
    READ_A(cur, 0);
    __builtin_amdgcn_s_barrier();
    __builtin_amdgcn_s_setprio(1);
    MFMA_BLK(0);
    __builtin_amdgcn_s_setprio(0);
    READ_A(cur, 4);
    __builtin_amdgcn_s_setprio(1);
    MFMA_BLK(1);
    __builtin_amdgcn_s_setprio(0);
  }

  // Epilogue: lane holds C[row=m0+wr*128+i*16+l15][cols n0+wc*64+j*16+q*4 .. +3]
#pragma unroll
  for (int i = 0; i < 8; ++i) {
    const int row = m0 + wr * 128 + i * 16 + l15;
    const float rcp = rd ? __builtin_amdgcn_rcpf(rd[row]) : 1.0f;
#pragma unroll
    for (int j = 0; j < 4; ++j) {
      const int colb = n0 + wc * 64 + j * 16 + q * 4;
      floatx4 v = acc[i][j];
      if (rd) { v[0] *= rcp; v[1] *= rcp; v[2] *= rcp; v[3] *= rcp; }
      if (bias) {
        const float4 bi = *(const float4*)&bias[colb];
        v[0] += bi.x; v[1] += bi.y; v[2] += bi.z; v[3] += bi.w;
      }
      if (Cb) *(short4v*)&Cb[(long long)bz * sC + (long long)row * ldc + colb] = pack4(v[0], v[1], v[2], v[3]);
      else    *(floatx4*)&Cf[(long long)bz * sC + (long long)row * ldc + colb] = v;
    }
  }
}

// ---------------------------------------------------------------------------
// Fused scores + group + exp, paired-row swizzle in the QK^T loop.
// (round-0 form: the 128²/4-wave quadrant is proven-null for deep phasing,
//  so this keeps the simple single-buffer loop.)
// W[b][m][n] = exp(q.k*scale) * (a + (1-a)*gw_m.gw_n);  L[row] += sum exp.
// ---------------------------------------------------------------------------
__global__ __launch_bounds__(256) void score_weights(
    const unsigned short* __restrict__ qkv, const unsigned short* __restrict__ gw,
    unsigned short* __restrict__ Wout, float* __restrict__ L,
    const float* __restrict__ alpha)
{
  const int tid  = threadIdx.x;
  const int lane = tid & 63;
  const int wave = tid >> 6;
  const int wr = wave >> 1, wc = wave & 1;
  const int n0 = blockIdx.x * 128;
  const int m0 = blockIdx.y * 128;
  const int b  = blockIdx.z;

  const int l15 = lane & 15;
  const int q   = lane >> 4;
  const int q8  = q * 8;

  // ---- group phase: direct-from-global frags, K=64 (cols 49..63 zero) ----
  const unsigned short* gq = gw + ((long long)(b * 1024 + m0 + wr * 64)) * 64;
  const unsigned short* gk = gw + ((long long)(b * 1024 + n0 + wc * 64)) * 64;
  floatx4 gacc[4][4];
#pragma unroll
  for (int i = 0; i < 4; ++i)
#pragma unroll
    for (int j = 0; j < 4; ++j) gacc[i][j] = floatx4{0.f, 0.f, 0.f, 0.f};
#pragma unroll
  for (int ks = 0; ks < 2; ++ks) {
    short8 af[4], bfv[4];
#pragma unroll
    for (int i = 0; i < 4; ++i) af[i]  = *(const short8*)&gq[(long long)(i * 16 + l15) * 64 + ks * 32 + q8];
#pragma unroll
    for (int j = 0; j < 4; ++j) bfv[j] = *(const short8*)&gk[(long long)(j * 16 + l15) * 64 + ks * 32 + q8];
#pragma unroll
    for (int i = 0; i < 4; ++i)
#pragma unroll
      for (int j = 0; j < 4; ++j)
        gacc[i][j] = __builtin_amdgcn_mfma_f32_16x16x32_bf16(bfv[j], af[i], gacc[i][j], 0, 0, 0);
  }
  const float aa    = 1.0f / (1.0f + __expf(-alpha[0]));
  const float onema = 1.0f - aa;
  half2v gfp[4][4][2];
#pragma unroll
  for (int i = 0; i < 4; ++i)
#pragma unroll
    for (int j = 0; j < 4; ++j) {
      gfp[i][j][0] = half2v{(_Float16)(aa + onema * gacc[i][j][0]),
                            (_Float16)(aa + onema * gacc[i][j][1])};
      gfp[i][j][1] = half2v{(_Float16)(aa + onema * gacc[i][j][2]),
                            (_Float16)(aa + onema * gacc[i][j][3])};
    }

  // ---- QK^T loop, BK=32 paired-row swizzle ----
  const unsigned short* Aq = qkv + ((long long)(b * 1024 + m0)) * 2304;        // q cols 0..767
  const unsigned short* Bk = qkv + ((long long)(b * 1024 + n0)) * 2304 + 768;  // k cols 768..1535

  __shared__ unsigned short As[128 * 32];
  __shared__ unsigned short Bs[128 * 32];

  floatx4 sacc[4][4];
#pragma unroll
  for (int i = 0; i < 4; ++i)
#pragma unroll
    for (int j = 0; j < 4; ++j) sacc[i][j] = floatx4{0.f, 0.f, 0.f, 0.f};

  const int t    = (lane & 7) ^ (lane >> 3);
  const int srow = 2 * (lane >> 3) + (t >> 2);
  const int scol = (t & 3) * 8;
  const unsigned short* ga0 = Aq + (long long)(wave * 32 + srow) * 2304 + scol;
  const unsigned short* ga1 = ga0 + 16LL * 2304;
  const unsigned short* gb0 = Bk + (long long)(wave * 32 + srow) * 2304 + scol;
  const unsigned short* gb1 = gb0 + 16LL * 2304;
  unsigned short* lA0 = As + wave * 1024;
  unsigned short* lA1 = lA0 + 512;
  unsigned short* lB0 = Bs + wave * 1024;
  unsigned short* lB1 = lB0 + 512;

  const int rofs = (l15 >> 1) * 64 + (((q + 4 * (l15 & 1)) ^ (l15 >> 1)) * 8);

  for (int kt = 0; kt < 768; kt += 32) {
    __syncthreads();
    stage16(ga0 + kt, lA0);
    stage16(ga1 + kt, lA1);
    stage16(gb0 + kt, lB0);
    stage16(gb1 + kt, lB1);
    __syncthreads();
    short8 af[4], bfv[4];
#pragma unroll
    for (int i = 0; i < 4; ++i) af[i]  = *(const short8*)&As[(wr * 32 + i * 8) * 64 + rofs];
#pragma unroll
    for (int j = 0; j < 4; ++j) bfv[j] = *(const short8*)&Bs[(wc * 32 + j * 8) * 64 + rofs];
#pragma unroll
    for (int i = 0; i < 4; ++i)
#pragma unroll
      for (int j = 0; j < 4; ++j)
        sacc[i][j] = __builtin_amdgcn_mfma_f32_16x16x32_bf16(bfv[j], af[i], sacc[i][j], 0, 0, 0);
  }

  const float scale = 0.03608439182435161f;  // 768^-0.5
  unsigned short* Wb = Wout + ((long long)b << 20);

#pragma unroll
  for (int i = 0; i < 4; ++i) {
    const int row = m0 + wr * 64 + i * 16 + l15;
    float ls = 0.0f;
#pragma unroll
    for (int j = 0; j < 4; ++j) {
      const int colb = n0 + wc * 64 + j * 16 + q * 4;
      float e0 = __expf(sacc[i][j][0] * scale);
      float e1 = __expf(sacc[i][j][1] * scale);
      float e2 = __expf(sacc[i][j][2] * scale);
      float e3 = __expf(sacc[i][j][3] * scale);
      ls += (e0 + e1) + (e2 + e3);
      *(short4v*)&Wb[(long long)row * 1024 + colb] =
        pack4(e0 * (float)gfp[i][j][0][0], e1 * (float)gfp[i][j][0][1],
              e2 * (float)gfp[i][j][1][0], e3 * (float)gfp[i][j][1][1]);
    }
    ls += __shfl_xor(ls, 16, 64);
    ls += __shfl_xor(ls, 32, 64);
    if (lane < 16) atomicAdd(&L[b * 1024 + row], ls);
  }
}

// gw[row][0..63] = softmax(q_row @ W_gp) padded with zeros (cols 49..63).
__global__ __launch_bounds__(256) void gw_kernel(
    const unsigned short* __restrict__ qkv, const unsigned short* __restrict__ WgpT,
    unsigned short* __restrict__ gw)
{
  const int wave = threadIdx.x >> 6;
  const int lane = threadIdx.x & 63;
  const long long row = (long long)blockIdx.x * 4 + wave;
  const unsigned short* q = qkv + row * 2304;
  float qv[12];
#pragma unroll
  for (int j = 0; j < 12; ++j) qv[j] = b2f(q[lane + 64 * j]);

  float logit = -1e30f;
  for (int g = 0; g < 49; ++g) {
    const unsigned short* wg = WgpT + g * 768;
    float acc = 0.0f;
#pragma unroll
    for (int j = 0; j < 12; ++j) acc += qv[j] * b2f(wg[lane + 64 * j]);
#pragma unroll
    for (int m = 1; m < 64; m <<= 1) acc += __shfl_xor(acc, m, 64);
    if (lane == g) logit = acc;
  }
  float mx = logit;
#pragma unroll
  for (int m = 1; m < 64; m <<= 1) mx = fmaxf(mx, __shfl_xor(mx, m, 64));
  const float e = (lane < 49) ? __expf(logit - mx) : 0.0f;
  float s = e;
#pragma unroll
  for (int m = 1; m < 64; m <<= 1) s += __shfl_xor(s, m, 64);
  gw[row * 64 + lane] = f2b(e / s);
}

__global__ void convert_f2b(const float* __restrict__ in, unsigned short* __restrict__ out, long long n)
{
  long long i = ((long long)blockIdx.x * 256 + threadIdx.x) * 4;
  if (i + 3 >= n) {
    for (long long k = i; k < n; ++k) out[k] = f2b(in[k]);
    return;
  }
  float4 v = *(const float4*)(in + i);
  out[i + 0] = f2b(v.x);
  out[i + 1] = f2b(v.y);
  out[i + 2] = f2b(v.z);
  out[i + 3] = f2b(v.w);
}

__global__ void transpose_f2b(const float* __restrict__ in, unsigned short* __restrict__ out,
                              int R, int C, int ldin, int ldout)
{
  __shared__ unsigned short t[32][33];
  const int c0 = blockIdx.x * 32, r0 = blockIdx.y * 32;
  for (int i = threadIdx.y; i < 32; i += 8) {
    const int r = r0 + i, c = c0 + threadIdx.x;
    if (r < R && c < C) t[i][threadIdx.x] = f2b(in[(long long)r * ldin + c]);
  }
  __syncthreads();
  for (int i = threadIdx.y; i < 32; i += 8) {
    const int r = c0 + i, c = r0 + threadIdx.x;
    if (r < C && c < R) out[(long long)r * ldout + c] = t[threadIdx.x][i];
  }
}

extern "C" void kernel_launch(void* const* d_in, const int* in_sizes, int n_in,
                              void* d_out, int out_size, void* d_ws, size_t ws_size,
                              hipStream_t stream)
{
  const float* x      = (const float*)d_in[0];
  const float* W_qkv  = (const float*)d_in[1];
  const float* b_qkv  = (const float*)d_in[2];
  const float* W_proj = (const float*)d_in[3];
  const float* b_proj = (const float*)d_in[4];
  const float* W_gp   = (const float*)d_in[5];
  const float* alpha  = (const float*)d_in[6];

  char* p = (char*)d_ws;
  auto alloc = [&](size_t bytes) { char* r = p; p += (bytes + 255) & ~255ULL; return r; };
  unsigned short* qkv    = (unsigned short*)alloc(16384ULL * 2304 * 2);   // q|k|v interleaved rows
  unsigned short* xb     = (unsigned short*)alloc(16384ULL * 768 * 2);
  unsigned short* WqkvT  = (unsigned short*)alloc(2304ULL * 768 * 2);
  unsigned short* WprojT = (unsigned short*)alloc(768ULL * 768 * 2);
  unsigned short* WgpT   = (unsigned short*)alloc(49ULL * 768 * 2);
  unsigned short* gwbuf  = (unsigned short*)alloc(16384ULL * 64 * 2);
  float*          Lbuf   = (float*)alloc(16384ULL * 4);
  unsigned short* wmat   = (unsigned short*)alloc(16ULL * 1024 * 1024 * 2);
  unsigned short* vpT    = (unsigned short*)alloc(16ULL * 768 * 1024 * 2); // (v @ W_proj)^T per batch

  const dim3 blk256(256);
  const dim3 blk512(512);
  const dim3 tb(32, 8);

  // input conversions / transposes (fp32 -> bf16)
  convert_f2b<<<dim3(12288), blk256, 0, stream>>>(x, xb, 16384LL * 768);
  transpose_f2b<<<dim3(72, 24), tb, 0, stream>>>(W_qkv, WqkvT, 768, 2304, 2304, 768);
  transpose_f2b<<<dim3(24, 24), tb, 0, stream>>>(W_proj, WprojT, 768, 768, 768, 768);
  transpose_f2b<<<dim3(2, 24), tb, 0, stream>>>(W_gp, WgpT, 768, 49, 49, 768);

  // qkv = x @ W_qkv + b_qkv   (256² engine; 576 = 8 xcd * 8 ytiles * 9 xtiles)
  gemm256<1><<<dim3(576, 1, 1), blk512, 0, stream>>>(xb, WqkvT, qkv, (float*)0,
                                                     (const float*)0, b_qkv,
                                                     768, 768, 768, 2304, 0, 0, 0, 0);

  // gw = softmax(q @ W_gp), padded to 64
  gw_kernel<<<dim3(4096), blk256, 0, stream>>>(qkv, WgpT, gwbuf);

  hipMemsetAsync(Lbuf, 0, 16384 * 4, stream);

  // weights (unnormalized) + L
  score_weights<<<dim3(8, 8, 16), blk256, 0, stream>>>(qkv, gwbuf, wmat, Lbuf, alpha);

  // vpT[b][768][1024] = (v @ W_proj)^T = W_proj^T . v^T
  //   C[n][m] = sum_k WprojT[n][k] * v[m][k]; A=WprojT (shared), B=v rows of qkv
  gemm256<0><<<dim3(4, 3, 16), blk512, 0, stream>>>(WprojT, qkv + 1536, vpT, (float*)0,
                                                    (const float*)0, (const float*)0,
                                                    768, 768, 2304, 1024,
                                                    0, 1024LL * 2304, 768LL * 1024, 0);

  // out[m][n] = (1/L[m]) * sum_k wmat[m][k] * vpT[n][k] + b_proj[n]   (fp32 out)
  gemm256<0><<<dim3(3, 4, 16), blk512, 0, stream>>>(wmat, vpT, (unsigned short*)0, (float*)d_out,
                                                    Lbuf, b_proj,
                                                    1024, 1024, 1024, 768,
                                                    1024LL * 1024, 768LL * 1024, 1024LL * 768, 1024);
}

// Round 5
// 370.308 us; speedup vs baseline: 1.1984x; 1.1464x over previous
//
#include <hip/hip_runtime.h>
#include <stdint.h>

typedef __attribute__((ext_vector_type(8))) short short8;
typedef __attribute__((ext_vector_type(4))) short short4v;
typedef __attribute__((ext_vector_type(4))) float floatx4;
typedef _Float16 half2v __attribute__((ext_vector_type(2)));

__device__ __forceinline__ float b2f(unsigned short u) {
  union { unsigned int i; float f; } v; v.i = ((unsigned int)u) << 16; return v.f;
}
__device__ __forceinline__ unsigned short f2b(float f) {
  union { float f; unsigned int i; } v; v.f = f;
  unsigned int i = v.i;
  return (unsigned short)((i + 0x7FFFu + ((i >> 16) & 1u)) >> 16);
}
__device__ __forceinline__ short4v pack4(float a, float b, float c, float d) {
  short4v r;
  r[0] = (short)f2b(a); r[1] = (short)f2b(b); r[2] = (short)f2b(c); r[3] = (short)f2b(d);
  return r;
}

// global -> LDS 16B per lane. lds_base wave-uniform; HW adds lane*16B.
__device__ __forceinline__ void stage16(const unsigned short* g, unsigned short* lds_base) {
  __builtin_amdgcn_global_load_lds((__attribute__((address_space(1))) const unsigned int*)g,
                                   (__attribute__((address_space(3))) unsigned int*)lds_base,
                                   16, 0, 0);
}

// ---------------------------------------------------------------------------
// r3-verified 256x256 engine: BK=32, 8 waves, ring-3, 2 phases/tile,
// counted vmcnt(4), setprio, paired-row zero-conflict swizzle.
// SWZ>0: 1-D grid of 8*SWZ*9 blocks; xcd owns SWZ contiguous y-tiles.
// ---------------------------------------------------------------------------
template<int SWZ>
__global__ __launch_bounds__(512, 2) void gemm256(
    const unsigned short* __restrict__ A, const unsigned short* __restrict__ B,
    unsigned short* __restrict__ Cb, float* __restrict__ Cf,
    const float* __restrict__ rowdiv, const float* __restrict__ bias,
    int K, int lda, int ldb, int ldc,
    long long sA, long long sB, long long sC, long long sRD)
{
  const int tid  = threadIdx.x;
  const int lane = tid & 63;
  const int wave = tid >> 6;          // 0..7
  const int wr = wave >> 2;           // 0..1  (row half: 128 rows)
  const int wc = wave & 3;            // 0..3  (col quarter: 64 cols)
  int m0, n0;
  if (SWZ > 0) {
    const int lin  = blockIdx.x;
    const int xcd  = lin & 7;
    const int rem  = lin >> 3;
    const int yloc = rem / 9;
    const int x    = rem - yloc * 9;
    m0 = (xcd * SWZ + yloc) * 256;
    n0 = x * 256;
  } else {
    m0 = blockIdx.y * 256;
    n0 = blockIdx.x * 256;
  }
  const int bz = blockIdx.z;
  A += (long long)bz * sA;
  B += (long long)bz * sB;
  const float* rd = rowdiv ? rowdiv + (long long)bz * sRD : (const float*)0;

  __shared__ __align__(16) unsigned short lds[3 * 16384];

  floatx4 acc[8][4];
#pragma unroll
  for (int i = 0; i < 8; ++i)
#pragma unroll
    for (int j = 0; j < 4; ++j) acc[i][j] = floatx4{0.f, 0.f, 0.f, 0.f};

  const int t    = (lane & 7) ^ (lane >> 3);
  const int srow = 2 * (lane >> 3) + (t >> 2);
  const int scol = (t & 3) * 8;
  const unsigned short* ga0 = A + (long long)(m0 + wave * 32 + srow) * lda + scol;
  const unsigned short* ga1 = ga0 + 16LL * lda;
  const unsigned short* gb0 = B + (long long)(n0 + wave * 32 + srow) * ldb + scol;
  const unsigned short* gb1 = gb0 + 16LL * ldb;

  const int l15  = lane & 15;
  const int q    = lane >> 4;
  const int rofs = (l15 >> 1) * 64 + (((q + 4 * (l15 & 1)) ^ (l15 >> 1)) * 8);

  short8 af[4], bfv[4];

  auto STAGE_A = [&](int kt, int buf) {
    unsigned short* d = lds + buf * 16384 + wave * 1024;
    stage16(ga0 + kt, d);
    stage16(ga1 + kt, d + 512);
  };
  auto STAGE_B = [&](int kt, int buf) {
    unsigned short* d = lds + buf * 16384 + 8192 + wave * 1024;
    stage16(gb0 + kt, d);
    stage16(gb1 + kt, d + 512);
  };
  auto READ_A = [&](int buf, int base) {
    const unsigned short* Ab = lds + buf * 16384;
#pragma unroll
    for (int i = 0; i < 4; ++i)
      af[i] = *(const short8*)&Ab[(wr * 64 + (base + i) * 8) * 64 + rofs];
  };
  auto READ_B = [&](int buf) {
    const unsigned short* Bb = lds + buf * 16384 + 8192;
#pragma unroll
    for (int j = 0; j < 4; ++j)
      bfv[j] = *(const short8*)&Bb[(wc * 32 + j * 8) * 64 + rofs];
  };
  auto MFMA_BLK = [&](int h) {
#pragma unroll
    for (int i = 0; i < 4; ++i)
#pragma unroll
      for (int j = 0; j < 4; ++j)
        acc[h * 4 + i][j] = __builtin_amdgcn_mfma_f32_16x16x32_bf16(bfv[j], af[i], acc[h * 4 + i][j], 0, 0, 0);
  };

  const int nt = K >> 5;
  int cur = 0;

  STAGE_A(0, 0);  STAGE_B(0, 0);
  STAGE_A(32, 1); STAGE_B(32, 1);
  asm volatile("s_waitcnt vmcnt(4)" ::: "memory");
  __builtin_amdgcn_s_barrier();

  for (int tt = 0; tt < nt - 2; ++tt) {
    const int nb  = (cur == 0) ? 2 : cur - 1;
    const int kt2 = (tt + 2) << 5;
    READ_B(cur);
    READ_A(cur, 0);
    STAGE_A(kt2, nb);
    __builtin_amdgcn_s_barrier();
    __builtin_amdgcn_s_setprio(1);
    MFMA_BLK(0);
    __builtin_amdgcn_s_setprio(0);
    __builtin_amdgcn_s_barrier();
    READ_A(cur, 4);
    STAGE_B(kt2, nb);
    __builtin_amdgcn_s_barrier();
    __builtin_amdgcn_s_setprio(1);
    MFMA_BLK(1);
    __builtin_amdgcn_s_setprio(0);
    asm volatile("s_waitcnt vmcnt(4)" ::: "memory");
    __builtin_amdgcn_s_barrier();
    cur = (cur == 2) ? 0 : cur + 1;
  }
  {
    READ_B(cur);
    READ_A(cur, 0);
    __builtin_amdgcn_s_barrier();
    __builtin_amdgcn_s_setprio(1);
    MFMA_BLK(0);
    __builtin_amdgcn_s_setprio(0);
    __builtin_amdgcn_s_barrier();
    READ_A(cur, 4);
    __builtin_amdgcn_s_setprio(1);
    MFMA_BLK(1);
    __builtin_amdgcn_s_setprio(0);
    asm volatile("s_waitcnt vmcnt(0)" ::: "memory");
    __builtin_amdgcn_s_barrier();
    cur = (cur == 2) ? 0 : cur + 1;
  }
  {
    READ_B(cur);
    READ_A(cur, 0);
    __builtin_amdgcn_s_barrier();
    __builtin_amdgcn_s_setprio(1);
    MFMA_BLK(0);
    __builtin_amdgcn_s_setprio(0);
    READ_A(cur, 4);
    __builtin_amdgcn_s_setprio(1);
    MFMA_BLK(1);
    __builtin_amdgcn_s_setprio(0);
  }

#pragma unroll
  for (int i = 0; i < 8; ++i) {
    const int row = m0 + wr * 128 + i * 16 + l15;
    const float rcp = rd ? __builtin_amdgcn_rcpf(rd[row]) : 1.0f;
#pragma unroll
    for (int j = 0; j < 4; ++j) {
      const int colb = n0 + wc * 64 + j * 16 + q * 4;
      floatx4 v = acc[i][j];
      if (rd) { v[0] *= rcp; v[1] *= rcp; v[2] *= rcp; v[3] *= rcp; }
      if (bias) {
        const float4 bi = *(const float4*)&bias[colb];
        v[0] += bi.x; v[1] += bi.y; v[2] += bi.z; v[3] += bi.w;
      }
      if (Cb) *(short4v*)&Cb[(long long)bz * sC + (long long)row * ldc + colb] = pack4(v[0], v[1], v[2], v[3]);
      else    *(floatx4*)&Cf[(long long)bz * sC + (long long)row * ldc + colb] = v;
    }
  }
}

// ---------------------------------------------------------------------------
// Fused scores + group + exp (unchanged, verified).
// ---------------------------------------------------------------------------
__global__ __launch_bounds__(256) void score_weights(
    const unsigned short* __restrict__ qkv, const unsigned short* __restrict__ gw,
    unsigned short* __restrict__ Wout, float* __restrict__ L,
    const float* __restrict__ alpha)
{
  const int tid  = threadIdx.x;
  const int lane = tid & 63;
  const int wave = tid >> 6;
  const int wr = wave >> 1, wc = wave & 1;
  const int n0 = blockIdx.x * 128;
  const int m0 = blockIdx.y * 128;
  const int b  = blockIdx.z;

  const int l15 = lane & 15;
  const int q   = lane >> 4;
  const int q8  = q * 8;

  const unsigned short* gq = gw + ((long long)(b * 1024 + m0 + wr * 64)) * 64;
  const unsigned short* gk = gw + ((long long)(b * 1024 + n0 + wc * 64)) * 64;
  floatx4 gacc[4][4];
#pragma unroll
  for (int i = 0; i < 4; ++i)
#pragma unroll
    for (int j = 0; j < 4; ++j) gacc[i][j] = floatx4{0.f, 0.f, 0.f, 0.f};
#pragma unroll
  for (int ks = 0; ks < 2; ++ks) {
    short8 af[4], bfv[4];
#pragma unroll
    for (int i = 0; i < 4; ++i) af[i]  = *(const short8*)&gq[(long long)(i * 16 + l15) * 64 + ks * 32 + q8];
#pragma unroll
    for (int j = 0; j < 4; ++j) bfv[j] = *(const short8*)&gk[(long long)(j * 16 + l15) * 64 + ks * 32 + q8];
#pragma unroll
    for (int i = 0; i < 4; ++i)
#pragma unroll
      for (int j = 0; j < 4; ++j)
        gacc[i][j] = __builtin_amdgcn_mfma_f32_16x16x32_bf16(bfv[j], af[i], gacc[i][j], 0, 0, 0);
  }
  const float aa    = 1.0f / (1.0f + __expf(-alpha[0]));
  const float onema = 1.0f - aa;
  half2v gfp[4][4][2];
#pragma unroll
  for (int i = 0; i < 4; ++i)
#pragma unroll
    for (int j = 0; j < 4; ++j) {
      gfp[i][j][0] = half2v{(_Float16)(aa + onema * gacc[i][j][0]),
                            (_Float16)(aa + onema * gacc[i][j][1])};
      gfp[i][j][1] = half2v{(_Float16)(aa + onema * gacc[i][j][2]),
                            (_Float16)(aa + onema * gacc[i][j][3])};
    }

  const unsigned short* Aq = qkv + ((long long)(b * 1024 + m0)) * 2304;
  const unsigned short* Bk = qkv + ((long long)(b * 1024 + n0)) * 2304 + 768;

  __shared__ unsigned short As[128 * 32];
  __shared__ unsigned short Bs[128 * 32];

  floatx4 sacc[4][4];
#pragma unroll
  for (int i = 0; i < 4; ++i)
#pragma unroll
    for (int j = 0; j < 4; ++j) sacc[i][j] = floatx4{0.f, 0.f, 0.f, 0.f};

  const int t    = (lane & 7) ^ (lane >> 3);
  const int srow = 2 * (lane >> 3) + (t >> 2);
  const int scol = (t & 3) * 8;
  const unsigned short* ga0 = Aq + (long long)(wave * 32 + srow) * 2304 + scol;
  const unsigned short* ga1 = ga0 + 16LL * 2304;
  const unsigned short* gb0 = Bk + (long long)(wave * 32 + srow) * 2304 + scol;
  const unsigned short* gb1 = gb0 + 16LL * 2304;
  unsigned short* lA0 = As + wave * 1024;
  unsigned short* lA1 = lA0 + 512;
  unsigned short* lB0 = Bs + wave * 1024;
  unsigned short* lB1 = lB0 + 512;

  const int rofs = (l15 >> 1) * 64 + (((q + 4 * (l15 & 1)) ^ (l15 >> 1)) * 8);

  for (int kt = 0; kt < 768; kt += 32) {
    __syncthreads();
    stage16(ga0 + kt, lA0);
    stage16(ga1 + kt, lA1);
    stage16(gb0 + kt, lB0);
    stage16(gb1 + kt, lB1);
    __syncthreads();
    short8 af[4], bfv[4];
#pragma unroll
    for (int i = 0; i < 4; ++i) af[i]  = *(const short8*)&As[(wr * 32 + i * 8) * 64 + rofs];
#pragma unroll
    for (int j = 0; j < 4; ++j) bfv[j] = *(const short8*)&Bs[(wc * 32 + j * 8) * 64 + rofs];
#pragma unroll
    for (int i = 0; i < 4; ++i)
#pragma unroll
      for (int j = 0; j < 4; ++j)
        sacc[i][j] = __builtin_amdgcn_mfma_f32_16x16x32_bf16(bfv[j], af[i], sacc[i][j], 0, 0, 0);
  }

  const float scale = 0.03608439182435161f;
  unsigned short* Wb = Wout + ((long long)b << 20);

#pragma unroll
  for (int i = 0; i < 4; ++i) {
    const int row = m0 + wr * 64 + i * 16 + l15;
    float ls = 0.0f;
#pragma unroll
    for (int j = 0; j < 4; ++j) {
      const int colb = n0 + wc * 64 + j * 16 + q * 4;
      float e0 = __expf(sacc[i][j][0] * scale);
      float e1 = __expf(sacc[i][j][1] * scale);
      float e2 = __expf(sacc[i][j][2] * scale);
      float e3 = __expf(sacc[i][j][3] * scale);
      ls += (e0 + e1) + (e2 + e3);
      *(short4v*)&Wb[(long long)row * 1024 + colb] =
        pack4(e0 * (float)gfp[i][j][0][0], e1 * (float)gfp[i][j][0][1],
              e2 * (float)gfp[i][j][1][0], e3 * (float)gfp[i][j][1][1]);
    }
    ls += __shfl_xor(ls, 16, 64);
    ls += __shfl_xor(ls, 32, 64);
    if (lane < 16) atomicAdd(&L[b * 1024 + row], ls);
  }
}

// ---------------------------------------------------------------------------
// NEW: MFMA-based gw. logits(16384x64) = q @ Wgp64^T (Wgp64: 64x768 bf16,
// rows 49..63 zero). Fused softmax over cols (mask >=49). Reuses the
// VERIFIED direct-from-global fragment convention of score_weights' group
// phase: acc[j] = mfma(bf[j], af, acc) -> lane(l15,q) holds
// C[row=l15][cols j*16+q*4 .. +3]. Each wave: 16 rows; block: 4 waves = 64
// rows; grid 256 blocks. Replaces the serial-reduction gw_kernel
// (49 sequential wave-reductions/row ~ est. >100 us).
// ---------------------------------------------------------------------------
__global__ __launch_bounds__(256) void gw_mfma(
    const unsigned short* __restrict__ qkv, const unsigned short* __restrict__ Wgp64,
    unsigned short* __restrict__ gw)
{
  const int lane = threadIdx.x & 63;
  const int wave = threadIdx.x >> 6;
  const int l15  = lane & 15;
  const int q    = lane >> 4;
  const int q8   = q * 8;
  const long long row0 = (long long)blockIdx.x * 64 + wave * 16;
  const unsigned short* A = qkv + row0 * 2304;          // q cols 0..767

  floatx4 acc[4];
#pragma unroll
  for (int j = 0; j < 4; ++j) acc[j] = floatx4{0.f, 0.f, 0.f, 0.f};

  for (int kt = 0; kt < 768; kt += 32) {
    short8 af = *(const short8*)&A[(long long)l15 * 2304 + kt + q8];
    short8 bf[4];
#pragma unroll
    for (int j = 0; j < 4; ++j)
      bf[j] = *(const short8*)&Wgp64[(j * 16 + l15) * 768 + kt + q8];
#pragma unroll
    for (int j = 0; j < 4; ++j)
      acc[j] = __builtin_amdgcn_mfma_f32_16x16x32_bf16(bf[j], af, acc[j], 0, 0, 0);
  }

  // lane holds logits[row0+l15][col=j*16+q*4+e]
  float mx = -1e30f;
#pragma unroll
  for (int j = 0; j < 4; ++j)
#pragma unroll
    for (int e = 0; e < 4; ++e) {
      const int col = j * 16 + q * 4 + e;
      if (col < 49) mx = fmaxf(mx, acc[j][e]);
    }
  mx = fmaxf(mx, __shfl_xor(mx, 16, 64));
  mx = fmaxf(mx, __shfl_xor(mx, 32, 64));

  float ev[4][4];
  float s = 0.0f;
#pragma unroll
  for (int j = 0; j < 4; ++j)
#pragma unroll
    for (int e = 0; e < 4; ++e) {
      const int col = j * 16 + q * 4 + e;
      const float x = (col < 49) ? __expf(acc[j][e] - mx) : 0.0f;
      ev[j][e] = x;
      s += x;
    }
  s += __shfl_xor(s, 16, 64);
  s += __shfl_xor(s, 32, 64);
  const float inv = 1.0f / s;

  unsigned short* out = gw + (row0 + l15) * 64;
#pragma unroll
  for (int j = 0; j < 4; ++j)
    *(short4v*)&out[j * 16 + q * 4] =
      pack4(ev[j][0] * inv, ev[j][1] * inv, ev[j][2] * inv, ev[j][3] * inv);
}

__global__ void convert_f2b(const float* __restrict__ in, unsigned short* __restrict__ out, long long n)
{
  long long i = ((long long)blockIdx.x * 256 + threadIdx.x) * 4;
  if (i + 3 >= n) {
    for (long long k = i; k < n; ++k) out[k] = f2b(in[k]);
    return;
  }
  float4 v = *(const float4*)(in + i);
  out[i + 0] = f2b(v.x);
  out[i + 1] = f2b(v.y);
  out[i + 2] = f2b(v.z);
  out[i + 3] = f2b(v.w);
}

__global__ void transpose_f2b(const float* __restrict__ in, unsigned short* __restrict__ out,
                              int R, int C, int ldin, int ldout)
{
  __shared__ unsigned short t[32][33];
  const int c0 = blockIdx.x * 32, r0 = blockIdx.y * 32;
  for (int i = threadIdx.y; i < 32; i += 8) {
    const int r = r0 + i, c = c0 + threadIdx.x;
    if (r < R && c < C) t[i][threadIdx.x] = f2b(in[(long long)r * ldin + c]);
  }
  __syncthreads();
  for (int i = threadIdx.y; i < 32; i += 8) {
    const int r = c0 + i, c = r0 + threadIdx.x;
    if (r < C && c < R) out[(long long)r * ldout + c] = t[threadIdx.x][i];
  }
}

extern "C" void kernel_launch(void* const* d_in, const int* in_sizes, int n_in,
                              void* d_out, int out_size, void* d_ws, size_t ws_size,
                              hipStream_t stream)
{
  const float* x      = (const float*)d_in[0];
  const float* W_qkv  = (const float*)d_in[1];
  const float* b_qkv  = (const float*)d_in[2];
  const float* W_proj = (const float*)d_in[3];
  const float* b_proj = (const float*)d_in[4];
  const float* W_gp   = (const float*)d_in[5];
  const float* alpha  = (const float*)d_in[6];

  char* p = (char*)d_ws;
  auto alloc = [&](size_t bytes) { char* r = p; p += (bytes + 255) & ~255ULL; return r; };
  unsigned short* qkv    = (unsigned short*)alloc(16384ULL * 2304 * 2);
  unsigned short* xb     = (unsigned short*)alloc(16384ULL * 768 * 2);
  unsigned short* WqkvT  = (unsigned short*)alloc(2304ULL * 768 * 2);
  unsigned short* WprojT = (unsigned short*)alloc(768ULL * 768 * 2);
  unsigned short* Wgp64  = (unsigned short*)alloc(64ULL * 768 * 2);   // zero-padded rows 49..63
  unsigned short* gwbuf  = (unsigned short*)alloc(16384ULL * 64 * 2);
  float*          Lbuf   = (float*)alloc(16384ULL * 4);
  unsigned short* wmat   = (unsigned short*)alloc(16ULL * 1024 * 1024 * 2);
  unsigned short* vpT    = (unsigned short*)alloc(16ULL * 768 * 1024 * 2);

  const dim3 blk256(256);
  const dim3 blk512(512);
  const dim3 tb(32, 8);

  convert_f2b<<<dim3(12288), blk256, 0, stream>>>(x, xb, 16384LL * 768);
  transpose_f2b<<<dim3(72, 24), tb, 0, stream>>>(W_qkv, WqkvT, 768, 2304, 2304, 768);
  transpose_f2b<<<dim3(24, 24), tb, 0, stream>>>(W_proj, WprojT, 768, 768, 768, 768);
  hipMemsetAsync(Wgp64, 0, 64ULL * 768 * 2, stream);
  transpose_f2b<<<dim3(2, 24), tb, 0, stream>>>(W_gp, Wgp64, 768, 49, 49, 768);

  // qkv = x @ W_qkv + b_qkv  (r3 config: 576 = 8 xcd * 8 ytiles * 9 xtiles)
  gemm256<8><<<dim3(576, 1, 1), blk512, 0, stream>>>(xb, WqkvT, qkv, (float*)0,
                                                     (const float*)0, b_qkv,
                                                     768, 768, 768, 2304, 0, 0, 0, 0);

  // gw = softmax(q @ W_gp), padded to 64 (MFMA version)
  gw_mfma<<<dim3(256), blk256, 0, stream>>>(qkv, Wgp64, gwbuf);

  hipMemsetAsync(Lbuf, 0, 16384 * 4, stream);

  score_weights<<<dim3(8, 8, 16), blk256, 0, stream>>>(qkv, gwbuf, wmat, Lbuf, alpha);

  // vpT[b][768][1024] = (v @ W_proj)^T
  gemm256<0><<<dim3(4, 3, 16), blk512, 0, stream>>>(WprojT, qkv + 1536, vpT, (float*)0,
                                                    (const float*)0, (const float*)0,
                                                    768, 768, 2304, 1024,
                                                    0, 1024LL * 2304, 768LL * 1024, 0);

  // out[m][n] = (1/L[m]) * sum_k wmat[m][k] * vpT[n][k] + b_proj[n]
  gemm256<0><<<dim3(3, 4, 16), blk512, 0, stream>>>(wmat, vpT, (unsigned short*)0, (float*)d_out,
                                                    Lbuf, b_proj,
                                                    1024, 1024, 1024, 768,
                                                    1024LL * 1024, 768LL * 1024, 1024LL * 768, 1024);
}